// Round 1
// baseline (99.569 us; speedup 1.0000x reference)
//
#include <hip/hip_runtime.h>

#define BATCH 4

__global__ void zero_kernel(float* out) { out[0] = 0.0f; }

__global__ __launch_bounds__(256) void chamfer_kernel(
    const float* __restrict__ pc1,
    const float* __restrict__ pc2,
    const float* __restrict__ pc1w,
    float* __restrict__ out, int N)
{
    const int dir  = blockIdx.z;          // 0: p1->p2 side, 1: p2->p1 side
    const int b    = blockIdx.y;          // batch
    const int lane = threadIdx.x & 63;
    const int wave = threadIdx.x >> 6;    // 0..3, each covers N/4 of j
    const int i    = blockIdx.x * 64 + lane;   // query index

    // Direction 0: density query=p1 vs cloud p2; dist query=p1w vs cloud p2
    // Direction 1: density query=p2 vs cloud p1; dist query=p2  vs cloud p1w
    const float *Qd, *Qw, *Cd, *Cw;
    if (dir == 0) { Qd = pc1; Qw = pc1w; Cd = pc2; Cw = pc2;  }
    else          { Qd = pc2; Qw = pc2;  Cd = pc1; Cw = pc1w; }
    const size_t base = (size_t)b * 3 * N;
    Qd += base; Qw += base; Cd += base; Cw += base;

    // query coords (SoA: x-plane, y-plane, z-plane each contiguous in point idx)
    const float qdx = Qd[i], qdy = Qd[N + i], qdz = Qd[2 * N + i];
    const float qwx = Qw[i], qwy = Qw[N + i], qwz = Qw[2 * N + i];

    // 4 independent accumulators to break dependency chains
    float s0 = 0.f, s1 = 0.f, s2 = 0.f, s3 = 0.f;
    float m0 = 3.4e38f, m1 = 3.4e38f, m2 = 3.4e38f, m3 = 3.4e38f;

    const int jc = N >> 2;          // per-wave j chunk (1024)
    const int j0 = wave * jc;
    for (int j = j0; j < j0 + jc; j += 4) {
        // wave-uniform float4 loads; L1 broadcast. 16B aligned (j%4==0, 3N%4==0).
        const float4 cdx = *(const float4*)(Cd + j);
        const float4 cdy = *(const float4*)(Cd + N + j);
        const float4 cdz = *(const float4*)(Cd + 2 * N + j);
        const float4 cwx = *(const float4*)(Cw + j);
        const float4 cwy = *(const float4*)(Cw + N + j);
        const float4 cwz = *(const float4*)(Cw + 2 * N + j);
        const float* px = &cdx.x; const float* py = &cdy.x; const float* pz = &cdz.x;
        const float* wx = &cwx.x; const float* wy = &cwy.x; const float* wz = &cwz.x;
        float* sacc[4] = { &s0, &s1, &s2, &s3 };
        float* macc[4] = { &m0, &m1, &m2, &m3 };
        #pragma unroll
        for (int u = 0; u < 4; ++u) {
            float dx = qdx - px[u], dy = qdy - py[u], dz = qdz - pz[u];
            float d2 = dx * dx + dy * dy + dz * dz;
            *sacc[u] += __expf(-0.5f * d2);
            float ex = qwx - wx[u], ey = qwy - wy[u], ez = qwz - wz[u];
            float e2 = ex * ex + ey * ey + ez * ez;
            *macc[u] = fminf(*macc[u], e2);
        }
    }
    const float dsum = (s0 + s1) + (s2 + s3);
    const float dmin = fminf(fminf(m0, m1), fminf(m2, m3));

    // combine the 4 wave partials per query via LDS
    __shared__ float s_sum[4][64];
    __shared__ float s_min[4][64];
    s_sum[wave][lane] = dsum;
    s_min[wave][lane] = dmin;
    __syncthreads();

    if (wave == 0) {
        float ts = (s_sum[0][lane] + s_sum[1][lane]) + (s_sum[2][lane] + s_sum[3][lane]);
        float tm = fminf(fminf(s_min[0][lane], s_min[1][lane]),
                         fminf(s_min[2][lane], s_min[3][lane]));
        // mask: mean_j exp(..)/2.5 > ZETA  <=>  sum_j exp(..) > ZETA*2.5*N
        const float thresh = 0.005f * 2.5f * (float)N;   // 51.2
        float c = (ts > thresh) ? fmaxf(tm - 0.01f, 0.0f) : 0.0f;
        // reduce 64 lanes
        #pragma unroll
        for (int off = 32; off > 0; off >>= 1)
            c += __shfl_down(c, off);
        if (lane == 0)
            atomicAdd(out, c * (1.0f / (float)(BATCH) / (float)N));
    }
}

extern "C" void kernel_launch(void* const* d_in, const int* in_sizes, int n_in,
                              void* d_out, int out_size, void* d_ws, size_t ws_size,
                              hipStream_t stream) {
    const float* pc1  = (const float*)d_in[0];
    const float* pc2  = (const float*)d_in[1];
    const float* pc1w = (const float*)d_in[2];
    float* out = (float*)d_out;
    const int N = in_sizes[0] / (3 * BATCH);   // 4096

    // harness poisons d_out once and never re-poisons between replays
    zero_kernel<<<1, 1, 0, stream>>>(out);

    dim3 grid(N / 64, BATCH, 2);
    chamfer_kernel<<<grid, 256, 0, stream>>>(pc1, pc2, pc1w, out, N);
}

// Round 2
// 67.968 us; speedup vs baseline: 1.4649x; 1.4649x over previous
//
#include <hip/hip_runtime.h>

#define BATCH 4
// sqrt(0.5*log2(e)): pre-scaling coords by this makes exp(-0.5*d2) == exp2(-d2_scaled)
#define SCALE 0.84932156f

__global__ void zero_kernel(float* out) { out[0] = 0.0f; }

static __device__ __forceinline__ float f4c(const float4& v, int u) {
    return ((const float*)&v)[u];
}

// Pack per (dir,b,group-of-4-j): [sx4, sy4, sz4, wx4, wy4, wz4] = 96B contiguous.
// s* = density cloud coords pre-scaled by SCALE; w* = distance cloud coords raw.
// dir0: density cloud = pc2, dist cloud = pc2. dir1: density = pc1, dist = pc1w.
__global__ __launch_bounds__(256) void pack_kernel(
    const float* __restrict__ pc1, const float* __restrict__ pc2,
    const float* __restrict__ pc1w, float* __restrict__ pack, int N)
{
    const int G = N >> 2;
    const int idx = blockIdx.x * blockDim.x + threadIdx.x;  // (dir*BATCH+b)*G + g
    if (idx >= 2 * BATCH * G) return;
    const int g   = idx % G;
    const int db  = idx / G;
    const int b   = db % BATCH;
    const int dir = db / BATCH;
    const float* dens = (dir == 0) ? pc2 : pc1;
    const float* dist = (dir == 0) ? pc2 : pc1w;
    const size_t base = (size_t)b * 3 * N + (size_t)g * 4;
    float4 sx = *(const float4*)(dens + base);
    float4 sy = *(const float4*)(dens + base + N);
    float4 sz = *(const float4*)(dens + base + 2 * N);
    float4 wx = *(const float4*)(dist + base);
    float4 wy = *(const float4*)(dist + base + N);
    float4 wz = *(const float4*)(dist + base + 2 * N);
    sx.x *= SCALE; sx.y *= SCALE; sx.z *= SCALE; sx.w *= SCALE;
    sy.x *= SCALE; sy.y *= SCALE; sy.z *= SCALE; sy.w *= SCALE;
    sz.x *= SCALE; sz.y *= SCALE; sz.z *= SCALE; sz.w *= SCALE;
    float4* o = (float4*)(pack + (size_t)idx * 24);
    o[0] = sx; o[1] = sy; o[2] = sz; o[3] = wx; o[4] = wy; o[5] = wz;
}

__global__ __launch_bounds__(512) void chamfer_kernel(
    const float* __restrict__ pc1, const float* __restrict__ pc2,
    const float* __restrict__ pc1w, const float* __restrict__ pack,
    float* __restrict__ out, int N)
{
    const int dir  = blockIdx.z;
    const int b    = blockIdx.y;
    const int lane = threadIdx.x & 63;
    const int wave = threadIdx.x >> 6;          // 0..7, each covers N/8 of j
    const int i    = blockIdx.x * 64 + lane;    // query index

    const float* Qd = (dir == 0) ? pc1  : pc2;  // density query (will be scaled)
    const float* Qw = (dir == 0) ? pc1w : pc2;  // distance query (raw)
    const size_t qb = (size_t)b * 3 * N;
    const float qdx = Qd[qb + i] * SCALE, qdy = Qd[qb + N + i] * SCALE,
                qdz = Qd[qb + 2 * N + i] * SCALE;
    const float qwx = Qw[qb + i], qwy = Qw[qb + N + i], qwz = Qw[qb + 2 * N + i];

    const int G   = N >> 2;     // groups of 4 j's
    const int gpw = G >> 3;     // groups per wave
    // readfirstlane -> provably wave-uniform address -> scalar (SMEM) loads
    int gbase = __builtin_amdgcn_readfirstlane((dir * BATCH + b) * G + wave * gpw);
    const float* p = pack + (size_t)gbase * 24;

    float s[4] = {0.f, 0.f, 0.f, 0.f};
    float m[4] = {3.4e38f, 3.4e38f, 3.4e38f, 3.4e38f};

    for (int it = 0; it < gpw; it += 2) {
        float4 L[12];
        #pragma unroll
        for (int t = 0; t < 12; ++t) L[t] = *(const float4*)(p + t * 4);
        p += 48;
        #pragma unroll
        for (int gg = 0; gg < 2; ++gg) {
            #pragma unroll
            for (int u = 0; u < 4; ++u) {
                float dx = qdx - f4c(L[gg * 6 + 0], u);
                float dy = qdy - f4c(L[gg * 6 + 1], u);
                float dz = qdz - f4c(L[gg * 6 + 2], u);
                float d2 = fmaf(dz, dz, fmaf(dy, dy, dx * dx));
                s[u] += __builtin_amdgcn_exp2f(-d2);   // neg is a free input modifier
                float ex = qwx - f4c(L[gg * 6 + 3], u);
                float ey = qwy - f4c(L[gg * 6 + 4], u);
                float ez = qwz - f4c(L[gg * 6 + 5], u);
                float e2 = fmaf(ez, ez, fmaf(ey, ey, ex * ex));
                m[u] = fminf(m[u], e2);
            }
        }
    }
    const float dsum = (s[0] + s[1]) + (s[2] + s[3]);
    const float dmin = fminf(fminf(m[0], m[1]), fminf(m[2], m[3]));

    __shared__ float ssum[8][64];
    __shared__ float smin[8][64];
    ssum[wave][lane] = dsum;
    smin[wave][lane] = dmin;
    __syncthreads();

    if (wave == 0) {
        float ts = 0.f, tm = 3.4e38f;
        #pragma unroll
        for (int w = 0; w < 8; ++w) {
            ts += ssum[w][lane];
            tm = fminf(tm, smin[w][lane]);
        }
        // mask: mean_j exp(..)/2.5 > ZETA  <=>  sum_j exp(..) > ZETA*2.5*N
        const float thresh = 0.005f * 2.5f * (float)N;
        float c = (ts > thresh) ? fmaxf(tm - 0.01f, 0.0f) : 0.0f;
        #pragma unroll
        for (int off = 32; off > 0; off >>= 1)
            c += __shfl_down(c, off);
        if (lane == 0)
            atomicAdd(out, c * (1.0f / ((float)BATCH * (float)N)));
    }
}

extern "C" void kernel_launch(void* const* d_in, const int* in_sizes, int n_in,
                              void* d_out, int out_size, void* d_ws, size_t ws_size,
                              hipStream_t stream) {
    const float* pc1  = (const float*)d_in[0];
    const float* pc2  = (const float*)d_in[1];
    const float* pc1w = (const float*)d_in[2];
    float* out = (float*)d_out;
    const int N = in_sizes[0] / (3 * BATCH);   // 4096
    const int G = N >> 2;

    float* pack = (float*)d_ws;                // 2*BATCH*G*96B = 768 KiB for N=4096

    zero_kernel<<<1, 1, 0, stream>>>(out);
    const int total = 2 * BATCH * G;
    pack_kernel<<<(total + 255) / 256, 256, 0, stream>>>(pc1, pc2, pc1w, pack, N);

    dim3 grid(N / 64, BATCH, 2);
    chamfer_kernel<<<grid, 512, 0, stream>>>(pc1, pc2, pc1w, pack, out, N);
}

// Round 3
// 50.039 us; speedup vs baseline: 1.9898x; 1.3583x over previous
//
#include <hip/hip_runtime.h>

#define BATCH 4
#define SCONST 0.72134752f   // 0.5*log2(e)

// One thread per group of 4 cloud points per (dir,b).
// cpack per group: [cx'(4), cy'(4), cz'(4), wx(4), wy(4), wz(4)] = 96B
//   c* = density-cloud coords * 2s ; w* = distance-cloud coords raw
// kpack per group: [c0(4) = -s*|c|^2, h0(4) = 0.5*|w|^2] = 32B
// dir0: density cloud = pc2, dist cloud = pc2. dir1: density = pc1, dist = pc1w.
__global__ __launch_bounds__(256) void pack_kernel(
    const float* __restrict__ pc1, const float* __restrict__ pc2,
    const float* __restrict__ pc1w, float* __restrict__ cpack,
    float* __restrict__ kpack, float* __restrict__ out, int N)
{
    const int G = N >> 2;
    const int idx = blockIdx.x * blockDim.x + threadIdx.x;
    if (idx == 0) out[0] = 0.0f;                 // fused output zeroing
    if (idx >= 2 * BATCH * G) return;
    const int g   = idx % G;
    const int db  = idx / G;
    const int b   = db % BATCH;
    const int dir = db / BATCH;
    const float* dens = (dir == 0) ? pc2 : pc1;
    const float* dist = (dir == 0) ? pc2 : pc1w;
    const size_t base = (size_t)b * 3 * N + (size_t)g * 4;
    float4 sx = *(const float4*)(dens + base);
    float4 sy = *(const float4*)(dens + base + N);
    float4 sz = *(const float4*)(dens + base + 2 * N);
    float4 wx = *(const float4*)(dist + base);
    float4 wy = *(const float4*)(dist + base + N);
    float4 wz = *(const float4*)(dist + base + 2 * N);
    float4 c0, h0;
    const float* sxp = &sx.x; const float* syp = &sy.x; const float* szp = &sz.x;
    const float* wxp = &wx.x; const float* wyp = &wy.x; const float* wzp = &wz.x;
    float* c0p = &c0.x; float* h0p = &h0.x;
    #pragma unroll
    for (int u = 0; u < 4; ++u) {
        c0p[u] = -SCONST * (sxp[u]*sxp[u] + syp[u]*syp[u] + szp[u]*szp[u]);
        h0p[u] = 0.5f    * (wxp[u]*wxp[u] + wyp[u]*wyp[u] + wzp[u]*wzp[u]);
    }
    const float twos = 2.0f * SCONST;
    sx.x *= twos; sx.y *= twos; sx.z *= twos; sx.w *= twos;
    sy.x *= twos; sy.y *= twos; sy.z *= twos; sy.w *= twos;
    sz.x *= twos; sz.y *= twos; sz.z *= twos; sz.w *= twos;
    float4* oc = (float4*)(cpack + (size_t)idx * 24);
    oc[0] = sx; oc[1] = sy; oc[2] = sz; oc[3] = wx; oc[4] = wy; oc[5] = wz;
    float4* ok = (float4*)(kpack + (size_t)idx * 8);
    ok[0] = c0; ok[1] = h0;
}

__global__ __launch_bounds__(1024, 8) void chamfer_kernel(
    const float* __restrict__ pc1, const float* __restrict__ pc2,
    const float* __restrict__ pc1w, const float* __restrict__ cpack,
    const float* __restrict__ kpack, float* __restrict__ out, int N)
{
    const int dir  = blockIdx.z;
    const int b    = blockIdx.y;
    const int lane = threadIdx.x & 63;
    const int wave = threadIdx.x >> 6;           // 0..15, each covers N/16 of j
    const int i    = blockIdx.x * 64 + lane;     // query index
    const int G    = N >> 2;                     // groups of 4 cloud points
    const int gpw  = G >> 4;                     // groups per wave
    const int db   = dir * BATCH + b;

    __shared__ float kc[8192];                   // G*8 floats = 32KB constants
    __shared__ float ssum[16][64];
    __shared__ float smin[16][64];

    // cooperative stage of the constants stream (coalesced)
    {
        const float4* ks = (const float4*)(kpack + (size_t)db * G * 8);
        float4* kd = (float4*)kc;
        const int nq = G * 2;                    // float4 count (2048)
        for (int t = threadIdx.x; t < nq; t += blockDim.x)
            kd[t] = ks[t];
    }

    // query data
    const float* Qd = (dir == 0) ? pc1  : pc2;   // density query (raw)
    const float* Qw = (dir == 0) ? pc1w : pc2;   // distance query
    const size_t qb = (size_t)b * 3 * N;
    const float qdx = Qd[qb + i], qdy = Qd[qb + N + i], qdz = Qd[qb + 2*N + i];
    const float wqx = Qw[qb + i], wqy = Qw[qb + N + i], wqz = Qw[qb + 2*N + i];
    const float nqx = -wqx, nqy = -wqy, nqz = -wqz;
    const float q0  = -SCONST * (qdx*qdx + qdy*qdy + qdz*qdz);
    const float qw2 = wqx*wqx + wqy*wqy + wqz*wqz;
    __syncthreads();

    // wave-uniform coord pointer -> scalar loads
    const int gbase = __builtin_amdgcn_readfirstlane(db * G + wave * gpw);
    const float* pp = cpack + (size_t)gbase * 24;
    int ka = wave * gpw * 8;                     // float index into kc

    float s0 = 0.f, s1 = 0.f, s2 = 0.f, s3 = 0.f;
    float m0 = 3.4e38f, m1 = 3.4e38f, m2 = 3.4e38f, m3 = 3.4e38f;

    #pragma unroll 2
    for (int gi = 0; gi < gpw; ++gi) {
        const float4 CX = *(const float4*)(pp);
        const float4 CY = *(const float4*)(pp + 4);
        const float4 CZ = *(const float4*)(pp + 8);
        const float4 WX = *(const float4*)(pp + 12);
        const float4 WY = *(const float4*)(pp + 16);
        const float4 WZ = *(const float4*)(pp + 20);
        const float4 C0 = *(const float4*)(kc + ka);      // ds_read_b128 -> VGPRs
        const float4 H0 = *(const float4*)(kc + ka + 4);
        pp += 24; ka += 8;
#define PAIR(CXc, CYc, CZc, WXc, WYc, WZc, C0c, H0c, sacc, macc)            \
        { float e = fmaf(qdx, CXc, C0c);                                     \
          e = fmaf(qdy, CYc, e);                                             \
          e = fmaf(qdz, CZc, e);                                             \
          sacc += __builtin_amdgcn_exp2f(e);                                 \
          float v = fmaf(nqx, WXc, H0c);                                     \
          v = fmaf(nqy, WYc, v);                                             \
          v = fmaf(nqz, WZc, v);                                             \
          macc = fminf(macc, v); }
        PAIR(CX.x, CY.x, CZ.x, WX.x, WY.x, WZ.x, C0.x, H0.x, s0, m0)
        PAIR(CX.y, CY.y, CZ.y, WX.y, WY.y, WZ.y, C0.y, H0.y, s1, m1)
        PAIR(CX.z, CY.z, CZ.z, WX.z, WY.z, WZ.z, C0.z, H0.z, s2, m2)
        PAIR(CX.w, CY.w, CZ.w, WX.w, WY.w, WZ.w, C0.w, H0.w, s3, m3)
#undef PAIR
    }

    ssum[wave][lane] = (s0 + s1) + (s2 + s3);
    smin[wave][lane] = fminf(fminf(m0, m1), fminf(m2, m3));
    __syncthreads();

    if (wave == 0) {
        float ts = 0.f, tm = 3.4e38f;
        #pragma unroll
        for (int w = 0; w < 16; ++w) {
            ts += ssum[w][lane];
            tm = fminf(tm, smin[w][lane]);
        }
        // true density sum = ts * 2^q0 ; mask iff > ZETA*2.5*N = 0.0125*N
        const float dens   = ts * __builtin_amdgcn_exp2f(q0);
        const float thresh = 0.0125f * (float)N;
        const float dmin   = 2.0f * tm + qw2;    // |q|^2 + 2*(0.5|c|^2 - q.c)
        float c = (dens > thresh) ? fmaxf(dmin - 0.01f, 0.0f) : 0.0f;
        #pragma unroll
        for (int off = 32; off > 0; off >>= 1)
            c += __shfl_down(c, off);
        if (lane == 0)
            atomicAdd(out, c * (1.0f / ((float)BATCH * (float)N)));
    }
}

extern "C" void kernel_launch(void* const* d_in, const int* in_sizes, int n_in,
                              void* d_out, int out_size, void* d_ws, size_t ws_size,
                              hipStream_t stream) {
    const float* pc1  = (const float*)d_in[0];
    const float* pc2  = (const float*)d_in[1];
    const float* pc1w = (const float*)d_in[2];
    float* out = (float*)d_out;
    const int N = in_sizes[0] / (3 * BATCH);     // 4096
    const int G = N >> 2;

    float* cpack = (float*)d_ws;                          // 2*B*G*96B = 768KB
    float* kpack = cpack + (size_t)2 * BATCH * G * 24;    // 2*B*G*32B = 256KB

    const int total = 2 * BATCH * G;
    pack_kernel<<<(total + 255) / 256, 256, 0, stream>>>(pc1, pc2, pc1w,
                                                         cpack, kpack, out, N);
    dim3 grid(N / 64, BATCH, 2);
    chamfer_kernel<<<grid, 1024, 0, stream>>>(pc1, pc2, pc1w, cpack, kpack, out, N);
}